// Round 6
// baseline (1095.143 us; speedup 1.0000x reference)
//
#include <hip/hip_runtime.h>

// x[t,b,h] = input·W_ihT + b_ih + hidden·W_hhT + b_hh  (M=32768, N=512, K=512+512)
// then in-place LIF scan over t.
// ARITHMETIC IS BIT-IDENTICAL TO THE ROUND-1 PASSING KERNEL: per output,
// ascending-k fmaf chain per phase (acc1: input·W_ih, acc2: hidden·W_hh),
// epilogue ((acc1 + b_ih) + acc2) + b_hh. Only scheduling/blocking changed:
// 128x128 tile, 8x8 outputs/thread (halves LDS bytes per FMA vs 8x4),
// rotation+duplication LDS layout (immediate-offset ds_reads, conflict-free),
// serial reg staging (no global_load_lds, no cross-FMA staging registers).

// LDS layout: per array, 128 rows x 16 chunks (4 f32 each) = 32 KiB.
// Logical chunk ch of row r lives at phys p = (ch + (r>>3)) & 7, duplicated
// at p+8. FMA read of (r, kc) = row*64 + ((r>>3)&7)*4 + kc*4  — monotone in
// kc (no wrap, thanks to duplication) => rowbase reg + kc*16B immediate.
// Conflicts: A-reads broadcast x16 with 4 distinct quads (free); W-reads
// 2-way (free, m136); staging writes 2-way (free).

#define FMA_PHASE(ACC)                                                        \
    _Pragma("unroll 4")                                                       \
    for (int kc = 0; kc < 8; ++kc) {                                          \
        float4 w4[8];                                                         \
        _Pragma("unroll")                                                     \
        for (int j = 0; j < 8; ++j)                                           \
            w4[j] = *(const float4*)(&Ws[(tn * 8 + j) * 64 + (tn & 7) * 4 + kc * 4]); \
        _Pragma("unroll")                                                     \
        for (int i = 0; i < 8; ++i) {                                         \
            const float4 a4 = *(const float4*)(&As[(tm * 8 + i) * 64 + (tm & 7) * 4 + kc * 4]); \
            _Pragma("unroll")                                                 \
            for (int j = 0; j < 8; ++j) {                                     \
                ACC[i][j] = fmaf(a4.x, w4[j].x, ACC[i][j]);                   \
                ACC[i][j] = fmaf(a4.y, w4[j].y, ACC[i][j]);                   \
                ACC[i][j] = fmaf(a4.z, w4[j].z, ACC[i][j]);                   \
                ACC[i][j] = fmaf(a4.w, w4[j].w, ACC[i][j]);                   \
            }                                                                 \
        }                                                                     \
    }

__global__ __launch_bounds__(256, 1) void gemm_x(
    const float* __restrict__ input, const float* __restrict__ hidden,
    const float* __restrict__ W_ih, const float* __restrict__ b_ih,
    const float* __restrict__ W_hh, const float* __restrict__ b_hh,
    float* __restrict__ out)
{
    __shared__ __align__(16) float As[128 * 64];   // 32 KiB
    __shared__ __align__(16) float Ws[128 * 64];   // 32 KiB

    const int tid = threadIdx.x;
    // XCD-chunked bijective swizzle: XCD x owns 128 consecutive tiles
    // (bm-major), so the 4 bn-tiles sharing an A-panel are dispatch-adjacent.
    const int tile = ((blockIdx.x & 7) << 7) | (blockIdx.x >> 3);
    const int bm = tile >> 2, bn = tile & 3;       // 256 x 4 tiles of 128x128
    const int m0 = bm * 128, n0 = bn * 128;
    const int tm = tid >> 4, tn = tid & 15;        // 8x8 outputs per thread

    // Staging map: slot lin = q*256+tid -> row = lin>>3, logical chunk = lin&7.
    int aoff[4], woff[4], lds0[4], lds1[4];
#pragma unroll
    for (int q = 0; q < 4; ++q) {
        int lin = q * 256 + tid, row = lin >> 3, ch = lin & 7;
        aoff[q] = (m0 + row) * 512 + ch * 4;
        woff[q] = (n0 + row) * 512 + ch * 4;
        int p = (ch + (row >> 3)) & 7;
        lds0[q] = row * 64 + p * 4;
        lds1[q] = row * 64 + (p + 8) * 4;
    }

    float acc1[8][8], acc2[8][8];
#pragma unroll
    for (int i = 0; i < 8; ++i)
#pragma unroll
        for (int j = 0; j < 8; ++j) { acc1[i][j] = 0.f; acc2[i][j] = 0.f; }

    // Unified 32-tile K loop: kt 0..15 = input·W_ih (acc1), 16..31 = hidden·W_hh (acc2).
#pragma unroll 1
    for (int kt = 0; kt < 32; ++kt) {
        const float* Ab = (kt < 16) ? input : hidden;
        const float* Wb = (kt < 16) ? W_ih : W_hh;
        const int kb = (kt & 15) * 32;
        float4 av[4], wv[4];
#pragma unroll
        for (int q = 0; q < 4; ++q) {
            av[q] = *(const float4*)(Ab + aoff[q] + kb);
            wv[q] = *(const float4*)(Wb + woff[q] + kb);
        }
        __syncthreads();                 // prior FMA reads done (loads fly past)
#pragma unroll
        for (int q = 0; q < 4; ++q) {
            *(float4*)(&As[lds0[q]]) = av[q];
            *(float4*)(&As[lds1[q]]) = av[q];
            *(float4*)(&Ws[lds0[q]]) = wv[q];
            *(float4*)(&Ws[lds1[q]]) = wv[q];
        }
        __syncthreads();
        if (kt < 16) { FMA_PHASE(acc1) } else { FMA_PHASE(acc2) }
    }

    // Epilogue: x = ((dot1 + b_ih) + dot2) + b_hh  (exact round-1 association)
    const int colb = n0 + tn * 8;
    const float4 bi0 = *(const float4*)(b_ih + colb);
    const float4 bi1 = *(const float4*)(b_ih + colb + 4);
    const float4 bh0 = *(const float4*)(b_hh + colb);
    const float4 bh1 = *(const float4*)(b_hh + colb + 4);
#pragma unroll
    for (int i = 0; i < 8; ++i) {
        float4 o0, o1;
        o0.x = ((acc1[i][0] + bi0.x) + acc2[i][0]) + bh0.x;
        o0.y = ((acc1[i][1] + bi0.y) + acc2[i][1]) + bh0.y;
        o0.z = ((acc1[i][2] + bi0.z) + acc2[i][2]) + bh0.z;
        o0.w = ((acc1[i][3] + bi0.w) + acc2[i][3]) + bh0.w;
        o1.x = ((acc1[i][4] + bi1.x) + acc2[i][4]) + bh1.x;
        o1.y = ((acc1[i][5] + bi1.y) + acc2[i][5]) + bh1.y;
        o1.z = ((acc1[i][6] + bi1.z) + acc2[i][6]) + bh1.z;
        o1.w = ((acc1[i][7] + bi1.w) + acc2[i][7]) + bh1.w;
        float* dst = out + (size_t)(m0 + tm * 8 + i) * 512 + colb;
        *(float4*)dst = o0;
        *(float4*)(dst + 4) = o1;
    }
}

// In-place LIF scan: one thread per (b,h) lane, sequential over t.
// Same per-element float ops as the passing rounds.
__global__ __launch_bounds__(256) void lif_scan(float* __restrict__ x)
{
    const int tid = blockIdx.x * blockDim.x + threadIdx.x;  // 0..32767
    float v = 0.f;
    for (int tb = 0; tb < 512; tb += 16) {
        float xv[16];
#pragma unroll
        for (int u = 0; u < 16; ++u)
            xv[u] = x[(tb + u) * 32768 + tid];
#pragma unroll
        for (int u = 0; u < 16; ++u) {
            v = v + (xv[u] - v) * 0.5f;
            float s = (v - 1.0f >= 0.0f) ? 1.0f : 0.0f;
            x[(tb + u) * 32768 + tid] = s;
            v = (1.0f - s) * v;
        }
    }
}

extern "C" void kernel_launch(void* const* d_in, const int* in_sizes, int n_in,
                              void* d_out, int out_size, void* d_ws, size_t ws_size,
                              hipStream_t stream) {
    const float* input  = (const float*)d_in[0];
    const float* hidden = (const float*)d_in[1];
    const float* W_ih   = (const float*)d_in[2];
    const float* b_ih   = (const float*)d_in[3];
    const float* W_hh   = (const float*)d_in[4];
    const float* b_hh   = (const float*)d_in[5];
    float* out = (float*)d_out;

    gemm_x<<<dim3(1024), dim3(256), 0, stream>>>(
        input, hidden, W_ih, b_ih, W_hh, b_hh, out);
    lif_scan<<<dim3(128), dim3(256), 0, stream>>>(out);
}

// Round 7
// 591.366 us; speedup vs baseline: 1.8519x; 1.8519x over previous
//
#include <hip/hip_runtime.h>

// x[t,b,h] = input·W_ihT + b_ih + hidden·W_hhT + b_hh  (M=32768, N=512, K=512+512)
// then in-place LIF scan over t.
// ARITHMETIC IS BIT-IDENTICAL TO THE ROUND-1 PASSING KERNEL: per output,
// ascending-k fmaf chain per phase, epilogue ((d1 + b_ih) + d2) + b_hh.
// Phase-split into two kernels so each holds one 8x8 accumulator set:
//   gemm_p1: partial = d1 + b_ih          (input · W_ih^T)
//   gemm_p2: x = (partial + d2) + b_hh    (hidden · W_hh^T)
// 8x8 per-thread tile halves LDS-read instrs per FMA vs round-1's 8x4
// (16 ds_read / 256 FMA), which was round-1's 63%-VALUBusy ceiling.
// Rotation LDS layout: phys chunk p = (ch + (row>>3)) & 7. Rotation offset is
// thread-uniform at read time (row>>3 == tm or tn), so reads are
// base + precomputed offset; A-reads are 16-lane broadcasts on 4 distinct
// bank-quads (free), W-reads 2-way (free). Writes at the 8-way floor (8/tile).

template <bool FIRST>
__global__ __launch_bounds__(256, 2) void gemm_phase(
    const float* __restrict__ A,      // [32768][512] input or hidden
    const float* __restrict__ W,      // [512][512]   W_ih or W_hh
    const float* __restrict__ bias,   // [512]        b_ih or b_hh
    float* __restrict__ out)          // partial / final x
{
    __shared__ __align__(16) float As[128 * 32];   // 16 KiB
    __shared__ __align__(16) float Ws[128 * 32];   // 16 KiB

    const int tid = threadIdx.x;
    // XCD-chunked bijective swizzle (1024 blocks): XCD x owns 128 consecutive
    // tiles bm-major, so the 4 bn-siblings sharing an A-panel are adjacent.
    const int tile = ((blockIdx.x & 7) << 7) | (blockIdx.x >> 3);
    const int bm = tile >> 2, bn = tile & 3;       // 256 x 4 tiles of 128x128
    const int m0 = bm * 128, n0 = bn * 128;
    const int tm = tid >> 4, tn = tid & 15;        // 8x8 outputs per thread

    // Staging maps: slot lin = q*256+tid -> row = lin>>3, chunk ch = lin&7,
    // phys quad p = (ch + (row>>3)) & 7.
    int ga[4], gw[4], lsa[4], lsw[4];
#pragma unroll
    for (int q = 0; q < 4; ++q) {
        int lin = q * 256 + tid, row = lin >> 3, ch = lin & 7;
        int p = (ch + (row >> 3)) & 7;
        ga[q]  = (m0 + row) * 512 + ch * 4;
        gw[q]  = (n0 + row) * 512 + ch * 4;
        lsa[q] = row * 32 + p * 4;
        lsw[q] = row * 32 + p * 4;
    }
    // Read-side rotated chunk offsets (thread-uniform rotation).
    int coa[8], cow[8];
#pragma unroll
    for (int kc = 0; kc < 8; ++kc) {
        coa[kc] = ((kc + tm) & 7) * 4;
        cow[kc] = ((kc + tn) & 7) * 4;
    }

    float acc[8][8];
#pragma unroll
    for (int i = 0; i < 8; ++i)
#pragma unroll
        for (int j = 0; j < 8; ++j) acc[i][j] = 0.f;

    // K loop: 16 tiles of BK=32, ascending k (bit-exact chain per output).
#pragma unroll 1
    for (int kt = 0; kt < 16; ++kt) {
        const int kb = kt * 32;
        float4 av[4], wv[4];
#pragma unroll
        for (int q = 0; q < 4; ++q) {
            av[q] = *(const float4*)(A + ga[q] + kb);
            wv[q] = *(const float4*)(W + gw[q] + kb);
        }
        __syncthreads();                 // prior-tile reads complete
#pragma unroll
        for (int q = 0; q < 4; ++q) {
            *(float4*)(&As[lsa[q]]) = av[q];
            *(float4*)(&Ws[lsw[q]]) = wv[q];
        }
        __syncthreads();
#pragma unroll
        for (int kc = 0; kc < 8; ++kc) {
            float4 w4[8];
#pragma unroll
            for (int j = 0; j < 8; ++j)
                w4[j] = *(const float4*)(&Ws[(tn * 8 + j) * 32 + cow[kc]]);
#pragma unroll
            for (int i = 0; i < 8; ++i) {
                const float4 a4 = *(const float4*)(&As[(tm * 8 + i) * 32 + coa[kc]]);
#pragma unroll
                for (int j = 0; j < 8; ++j) {
                    acc[i][j] = fmaf(a4.x, w4[j].x, acc[i][j]);
                    acc[i][j] = fmaf(a4.y, w4[j].y, acc[i][j]);
                    acc[i][j] = fmaf(a4.z, w4[j].z, acc[i][j]);
                    acc[i][j] = fmaf(a4.w, w4[j].w, acc[i][j]);
                }
            }
        }
    }

    // Epilogue. FIRST: partial = d1 + b_ih. SECOND: x = (partial + d2) + b_hh.
    const int colb = n0 + tn * 8;
    const float4 b0 = *(const float4*)(bias + colb);
    const float4 b1 = *(const float4*)(bias + colb + 4);
#pragma unroll
    for (int i = 0; i < 8; ++i) {
        float* dst = out + (size_t)(m0 + tm * 8 + i) * 512 + colb;
        float4 o0, o1;
        if (FIRST) {
            o0.x = acc[i][0] + b0.x;  o0.y = acc[i][1] + b0.y;
            o0.z = acc[i][2] + b0.z;  o0.w = acc[i][3] + b0.w;
            o1.x = acc[i][4] + b1.x;  o1.y = acc[i][5] + b1.y;
            o1.z = acc[i][6] + b1.z;  o1.w = acc[i][7] + b1.w;
        } else {
            const float4 p0 = *(const float4*)dst;
            const float4 p1 = *(const float4*)(dst + 4);
            o0.x = (p0.x + acc[i][0]) + b0.x;  o0.y = (p0.y + acc[i][1]) + b0.y;
            o0.z = (p0.z + acc[i][2]) + b0.z;  o0.w = (p0.w + acc[i][3]) + b0.w;
            o1.x = (p1.x + acc[i][4]) + b1.x;  o1.y = (p1.y + acc[i][5]) + b1.y;
            o1.z = (p1.z + acc[i][6]) + b1.z;  o1.w = (p1.w + acc[i][7]) + b1.w;
        }
        *(float4*)dst = o0;
        *(float4*)(dst + 4) = o1;
    }
}

// In-place LIF scan: one thread per (b,h) lane, sequential over t.
// Same per-element float ops as the passing rounds.
__global__ __launch_bounds__(256) void lif_scan(float* __restrict__ x)
{
    const int tid = blockIdx.x * blockDim.x + threadIdx.x;  // 0..32767
    float v = 0.f;
    for (int tb = 0; tb < 512; tb += 16) {
        float xv[16];
#pragma unroll
        for (int u = 0; u < 16; ++u)
            xv[u] = x[(tb + u) * 32768 + tid];
#pragma unroll
        for (int u = 0; u < 16; ++u) {
            v = v + (xv[u] - v) * 0.5f;
            float s = (v - 1.0f >= 0.0f) ? 1.0f : 0.0f;
            x[(tb + u) * 32768 + tid] = s;
            v = (1.0f - s) * v;
        }
    }
}

extern "C" void kernel_launch(void* const* d_in, const int* in_sizes, int n_in,
                              void* d_out, int out_size, void* d_ws, size_t ws_size,
                              hipStream_t stream) {
    const float* input  = (const float*)d_in[0];
    const float* hidden = (const float*)d_in[1];
    const float* W_ih   = (const float*)d_in[2];
    const float* b_ih   = (const float*)d_in[3];
    const float* W_hh   = (const float*)d_in[4];
    const float* b_hh   = (const float*)d_in[5];
    float* out = (float*)d_out;

    gemm_phase<true ><<<dim3(1024), dim3(256), 0, stream>>>(input,  W_ih, b_ih, out);
    gemm_phase<false><<<dim3(1024), dim3(256), 0, stream>>>(hidden, W_hh, b_hh, out);
    lif_scan<<<dim3(128), dim3(256), 0, stream>>>(out);
}

// Round 8
// 589.246 us; speedup vs baseline: 1.8585x; 1.0036x over previous
//
#include <hip/hip_runtime.h>

// x[t,b,h] = input·W_ihT + b_ih + hidden·W_hhT + b_hh  (M=32768, N=512, K=512+512)
// then in-place LIF scan over t.
// ARITHMETIC IS BIT-IDENTICAL TO THE ROUND-1 PASSING KERNEL: per output,
// ascending-k fmaf chain per phase, epilogue ((d1 + b_ih) + d2) + b_hh.
// Phase-split into two kernels so each holds one 8x8 accumulator set:
//   gemm_p1: partial = d1 + b_ih          (input · W_ih^T)
//   gemm_p2: x = (partial + d2) + b_hh    (hidden · W_hh^T)
// Round-8 delta vs round 7: __launch_bounds__(256) (single-arg) — the (256,2)
// hint made the allocator pick 96 VGPRs and spill the 8x8 accumulator
// (WRITE_SIZE 418 MB vs 64 MB ideal, VALUBusy 47%). Round 6 proved the same
// inner loop allocates ~148 VGPRs spill-free when unconstrained.
// Rotation LDS layout: phys chunk p = (ch + (row>>3)) & 7; read rotation is
// thread-uniform (row>>3 == tm or tn). A-reads 16-lane broadcast on 4 distinct
// bank-quads (free), W-reads 2-way (free), writes at the 8-way floor.

template <bool FIRST>
__global__ __launch_bounds__(256) void gemm_phase(
    const float* __restrict__ A,      // [32768][512] input or hidden
    const float* __restrict__ W,      // [512][512]   W_ih or W_hh
    const float* __restrict__ bias,   // [512]        b_ih or b_hh
    float* __restrict__ out)          // partial / final x
{
    __shared__ __align__(16) float As[128 * 32];   // 16 KiB
    __shared__ __align__(16) float Ws[128 * 32];   // 16 KiB

    const int tid = threadIdx.x;
    // XCD-chunked bijective swizzle (1024 blocks): XCD x owns 128 consecutive
    // tiles bm-major, so the 4 bn-siblings sharing an A-panel are adjacent.
    const int tile = ((blockIdx.x & 7) << 7) | (blockIdx.x >> 3);
    const int bm = tile >> 2, bn = tile & 3;       // 256 x 4 tiles of 128x128
    const int m0 = bm * 128, n0 = bn * 128;
    const int tm = tid >> 4, tn = tid & 15;        // 8x8 outputs per thread

    // Staging maps: slot lin = q*256+tid -> row = lin>>3, chunk ch = lin&7,
    // phys quad p = (ch + (row>>3)) & 7.
    int ga[4], gw[4], lsa[4];
#pragma unroll
    for (int q = 0; q < 4; ++q) {
        int lin = q * 256 + tid, row = lin >> 3, ch = lin & 7;
        int p = (ch + (row >> 3)) & 7;
        ga[q]  = (m0 + row) * 512 + ch * 4;
        gw[q]  = (n0 + row) * 512 + ch * 4;
        lsa[q] = row * 32 + p * 4;
    }

    float acc[8][8];
#pragma unroll
    for (int i = 0; i < 8; ++i)
#pragma unroll
        for (int j = 0; j < 8; ++j) acc[i][j] = 0.f;

    // K loop: 16 tiles of BK=32, ascending k (bit-exact chain per output).
#pragma unroll 1
    for (int kt = 0; kt < 16; ++kt) {
        const int kb = kt * 32;
        float4 av[4], wv[4];
#pragma unroll
        for (int q = 0; q < 4; ++q) {
            av[q] = *(const float4*)(A + ga[q] + kb);
            wv[q] = *(const float4*)(W + gw[q] + kb);
        }
        __syncthreads();                 // prior-tile reads complete
#pragma unroll
        for (int q = 0; q < 4; ++q) {
            *(float4*)(&As[lsa[q]]) = av[q];
            *(float4*)(&Ws[lsa[q]]) = wv[q];
        }
        __syncthreads();
#pragma unroll
        for (int kc = 0; kc < 8; ++kc) {
            const int coa = ((kc + tm) & 7) * 4;   // thread-uniform rotation
            const int cow = ((kc + tn) & 7) * 4;
            float4 w4[8];
#pragma unroll
            for (int j = 0; j < 8; ++j)
                w4[j] = *(const float4*)(&Ws[(tn * 8 + j) * 32 + cow]);
#pragma unroll
            for (int i = 0; i < 8; ++i) {
                const float4 a4 = *(const float4*)(&As[(tm * 8 + i) * 32 + coa]);
#pragma unroll
                for (int j = 0; j < 8; ++j) {
                    acc[i][j] = fmaf(a4.x, w4[j].x, acc[i][j]);
                    acc[i][j] = fmaf(a4.y, w4[j].y, acc[i][j]);
                    acc[i][j] = fmaf(a4.z, w4[j].z, acc[i][j]);
                    acc[i][j] = fmaf(a4.w, w4[j].w, acc[i][j]);
                }
            }
        }
    }

    // Epilogue. FIRST: partial = d1 + b_ih. SECOND: x = (partial + d2) + b_hh.
    const int colb = n0 + tn * 8;
    const float4 b0 = *(const float4*)(bias + colb);
    const float4 b1 = *(const float4*)(bias + colb + 4);
#pragma unroll
    for (int i = 0; i < 8; ++i) {
        float* dst = out + (size_t)(m0 + tm * 8 + i) * 512 + colb;
        float4 o0, o1;
        if (FIRST) {
            o0.x = acc[i][0] + b0.x;  o0.y = acc[i][1] + b0.y;
            o0.z = acc[i][2] + b0.z;  o0.w = acc[i][3] + b0.w;
            o1.x = acc[i][4] + b1.x;  o1.y = acc[i][5] + b1.y;
            o1.z = acc[i][6] + b1.z;  o1.w = acc[i][7] + b1.w;
        } else {
            const float4 p0 = *(const float4*)dst;
            const float4 p1 = *(const float4*)(dst + 4);
            o0.x = (p0.x + acc[i][0]) + b0.x;  o0.y = (p0.y + acc[i][1]) + b0.y;
            o0.z = (p0.z + acc[i][2]) + b0.z;  o0.w = (p0.w + acc[i][3]) + b0.w;
            o1.x = (p1.x + acc[i][4]) + b1.x;  o1.y = (p1.y + acc[i][5]) + b1.y;
            o1.z = (p1.z + acc[i][6]) + b1.z;  o1.w = (p1.w + acc[i][7]) + b1.w;
        }
        *(float4*)dst = o0;
        *(float4*)(dst + 4) = o1;
    }
}

// In-place LIF scan: one thread per (b,h) lane, sequential over t.
// Same per-element float ops as the passing rounds.
__global__ __launch_bounds__(256) void lif_scan(float* __restrict__ x)
{
    const int tid = blockIdx.x * blockDim.x + threadIdx.x;  // 0..32767
    float v = 0.f;
    for (int tb = 0; tb < 512; tb += 16) {
        float xv[16];
#pragma unroll
        for (int u = 0; u < 16; ++u)
            xv[u] = x[(tb + u) * 32768 + tid];
#pragma unroll
        for (int u = 0; u < 16; ++u) {
            v = v + (xv[u] - v) * 0.5f;
            float s = (v - 1.0f >= 0.0f) ? 1.0f : 0.0f;
            x[(tb + u) * 32768 + tid] = s;
            v = (1.0f - s) * v;
        }
    }
}

extern "C" void kernel_launch(void* const* d_in, const int* in_sizes, int n_in,
                              void* d_out, int out_size, void* d_ws, size_t ws_size,
                              hipStream_t stream) {
    const float* input  = (const float*)d_in[0];
    const float* hidden = (const float*)d_in[1];
    const float* W_ih   = (const float*)d_in[2];
    const float* b_ih   = (const float*)d_in[3];
    const float* W_hh   = (const float*)d_in[4];
    const float* b_hh   = (const float*)d_in[5];
    float* out = (float*)d_out;

    gemm_phase<true ><<<dim3(1024), dim3(256), 0, stream>>>(input,  W_ih, b_ih, out);
    gemm_phase<false><<<dim3(1024), dim3(256), 0, stream>>>(hidden, W_hh, b_hh, out);
    lif_scan<<<dim3(128), dim3(256), 0, stream>>>(out);
}